// Round 7
// baseline (487.820 us; speedup 1.0000x reference)
//
#include <hip/hip_runtime.h>
#include <hip/hip_bf16.h>
#include <math.h>

// ---------------------------------------------------------------------------
// LSV Monte Carlo, round 7.
// 512 blocks x 512 threads (32 paths, 8 waves) -> 2 blocks/CU so the two
// per-step barrier drains overlap across blocks. Waves 0-6 run the 100x100
// MFMA GEMM (16-j tiles); every wave runs one (maturity, strike-tile) hedge
// for both 16-path tiles; wave 7 runs the vd/vv nets. H1 is XOR-swizzled
// [path][kc^(path&15)] so staged writes AND transposed B-frag reads are
// conflict-free. Per-step scalars (sqrt/exp/maturity) come from a 96-entry
// LDS table. Finalize (mean/var) fused via last-block-done atomic.
// ---------------------------------------------------------------------------

#define MC      16384
#define NSTEP   96
#define NPATH   32
#define BLOCK   512
#define NGROUP  512
#define NPAIR   84

typedef short bf16x8 __attribute__((ext_vector_type(8)));
typedef float f32x4  __attribute__((ext_vector_type(4)));

union U8 { uint4 u; bf16x8 v; };
union BF2U { __hip_bfloat162 b; unsigned u; };

__device__ __forceinline__ unsigned bf16rne(float x) {   // setup-time only
    unsigned u = __float_as_uint(x);
    return (u + 0x7FFFu + ((u >> 16) & 1u)) >> 16;
}
__device__ __forceinline__ unsigned pk2(float lo, float hi) {
    BF2U t; t.b = __float22bfloat162_rn(make_float2(lo, hi));
    return t.u;
}
__device__ __forceinline__ float sp(float x) {
    return fmaxf(x, 0.f) + __logf(1.f + __expf(-fabsf(x)));
}

__global__ __launch_bounds__(BLOCK, 4)
void lsv_sim(const float* __restrict__ S0p,   const float* __restrict__ ratep,
             const float* __restrict__ z,     const float* __restrict__ zzg,
             const float* __restrict__ strikesg,
             const float* __restrict__ v0p,   const float* __restrict__ rhop,
             const float* __restrict__ svW1,  const float* __restrict__ svb1,
             const float* __restrict__ svW2,  const float* __restrict__ svb2,
             const float* __restrict__ svW3,  const float* __restrict__ svb3,
             const float* __restrict__ vhW1,  const float* __restrict__ vhb1,
             const float* __restrict__ vhW2,  const float* __restrict__ vhb2,
             const float* __restrict__ vdW1,  const float* __restrict__ vdb1,
             const float* __restrict__ vdW2,  const float* __restrict__ vdb2,
             const float* __restrict__ vvW1,  const float* __restrict__ vvb1,
             const float* __restrict__ vvW2,  const float* __restrict__ vvb2,
             const int*   __restrict__ mats,
             float* __restrict__ psum, float* __restrict__ psq,
             unsigned* __restrict__ cnt, float* __restrict__ out)
{
    __shared__ __align__(16) unsigned short H1c[NPATH * 16 * 8]; // 8 KB [path][slot][8]
    __shared__ __align__(16) float W1f[16 * 36];                 // 2.25 KB
    __shared__ __align__(16) float WH1f[16 * 36];                // 2.25 KB
    __shared__ __align__(16) float B2T[128], W3T[128];           // 1 KB
    __shared__ __align__(16) float4 STa[96], STb[96];            // 3 KB
    __shared__ float RED[8][32];                                 // 1 KB
    __shared__ float VDl[2][32], VVl[2][32];                     // 512 B
    __shared__ float PSs[32], PSq[32];                           // 256 B
    __shared__ float VW[128];                                    // 512 B
    __shared__ unsigned lastv;

    const int tid  = threadIdx.x;
    const int lane = tid & 63;
    const int w    = __builtin_amdgcn_readfirstlane(tid >> 6);   // 0..7
    const int quad = lane >> 4;
    const int col  = lane & 15;
    const int pidx = lane & 31;                 // this lane's path
    const int gpath = blockIdx.x * NPATH + pidx;

    const int hm    = w >> 1;                   // hedge maturity
    const int stile = w & 1;                    // hedge strike tile

    // ---- stage tables ------------------------------------------------------
    for (int e = tid; e < 128; e += BLOCK) {
        float v = 0.f;
        if      (e < 20)             v = vdW1[e];
        else if (e < 40)             v = vdb1[e - 20];
        else if (e < 60)             v = vdW2[e - 40];
        else if (e >= 64 && e < 84)  v = vvW1[e - 64];
        else if (e >= 84 && e < 104) v = vvb1[e - 84];
        else if (e >= 104 && e < 124)v = vvW2[e - 104];
        else if (e == 124)           v = vdb2[0];
        else if (e == 125)           v = vvb2[0];
        VW[e] = v;
        B2T[e] = (e < 100) ? svb2[e] : 0.f;
        W3T[e] = (e < 100) ? svW3[e] : 0.f;
    }
    for (int e = tid; e < 576; e += BLOCK) {       // W1f [kc][36]
        const int kc2 = e / 36, r6 = e - 36 * kc2;
        float v = 0.f;
        if (r6 < 32) {
            const int grp = r6 >> 3, kk = kc2 * 8 + (r6 & 7);
            if (kk < 100) v = (grp == 0) ? svW1[kk] : (grp == 1) ? svW1[100 + kk]
                            : (grp == 2) ? svW1[200 + kk] : svb1[kk];
        }
        W1f[e] = v;
    }
    for (int e = tid; e < 576; e += BLOCK) {       // WH1f [hm*4+quad][36]
        const int hq = e / 36, r6 = e - 36 * hq;
        const int hmm = hq >> 2, qq = hq & 3;
        float v = 0.f;
        if (r6 < 24) {
            const int grp = r6 >> 3, j = qq * 8 + (r6 & 7);
            if (j < 20)
                v = (grp == 0) ? vhW1[hmm * 40 + j] : (grp == 1) ? vhW1[hmm * 40 + 20 + j]
                                                    : vhb1[hmm * 20 + j];
        }
        WH1f[e] = v;
    }
    if (tid < 96) {                                // per-step scalar table
        const int i = tid;
        const float t0 = (float)i       * (1.f / 365.f);
        const float t1 = (float)(i + 1) * (1.f / 365.f);
        const float hh = t1 - t0;
        const float rr = ratep[0];
        const int  day = i + 1;
        const int  mm0 = mats[0], mm1 = mats[1], mm2 = mats[2], mm3 = mats[3];
        const int  idx = (day > mm0) + (day > mm1) + (day > mm2);
        const int  mday = (idx == 0) ? mm0 : (idx == 1) ? mm1 : (idx == 2) ? mm2 : mm3;
        STa[i] = make_float4(t0, hh, sqrtf(hh), __expf(-rr * t0));
        STb[i] = make_float4(__expf(-rr * t1), (float)idx, (day == mday) ? 1.f : 0.f, 0.f);
    }
    if (tid < 32) RED[7][tid] = 0.f;               // wave 7 never writes it

    // ---- uniform setup -----------------------------------------------------
    const float rate  = ratep[0];
    const float S0    = S0p[0];
    const float rho_t = tanhf(rhop[0]);
    const float srho  = sqrtf(1.f - rho_t * rho_t);
    const float b3    = svb3[0];

    // ---- invariant A-fragments (weights) in registers/AGPRs ----------------
    // main: wave w < 7 owns j-tile w: A[m=j_local=col][k=32c+8quad+e]
    bf16x8 Af[4];
#pragma unroll
    for (int c = 0; c < 4; c++) {
        U8 tt;
#pragma unroll
        for (int e2 = 0; e2 < 4; e2++) {
            const int k0 = 32 * c + 8 * quad + 2 * e2;
            const int j  = w * 16 + col;
            const float v0 = (k0     < 100 && j < 100) ? svW2[k0 * 100 + j]       : 0.f;
            const float v1 = (k0 + 1 < 100 && j < 100) ? svW2[(k0 + 1) * 100 + j] : 0.f;
            (&tt.u.x)[e2] = bf16rne(v0) | (bf16rne(v1) << 16);
        }
        Af[c] = tt.v;
    }
    // hedge: A[s_local=col][k=j=8quad+e], s = stile*16+col
    bf16x8 Ah;
    {
        U8 tt;
#pragma unroll
        for (int e2 = 0; e2 < 4; e2++) {
            const int j0 = 8 * quad + 2 * e2, j1 = j0 + 1;
            const int s  = stile * 16 + col;
            const float v0 = (j0 < 20 && s < 21) ? vhW2[hm * 420 + j0 * 21 + s] : 0.f;
            const float v1 = (j1 < 20 && s < 21) ? vhW2[hm * 420 + j1 * 21 + s] : 0.f;
            (&tt.u.x)[e2] = bf16rne(v0) | (bf16rne(v1) << 16);
        }
        Ah = tt.v;
    }
    float b2h[4], Ka[4];
#pragma unroll
    for (int r = 0; r < 4; r++) {
        const int s = stile * 16 + quad * 4 + r;
        b2h[r] = (s < 21) ? vhb2[hm * 21 + s] : 0.f;
        Ka[r]  = (s < 21) ? strikesg[s] : 1e30f;
    }

    // ---- per-path state (lane&31 = path; upper half mirrors lower) ---------
    float Slog = __logf(S0);
    float S    = __expf(Slog);
    float V    = (1.f / (1.f + __expf(-v0p[0]))) * 0.5f;
    f32x4 cv0 = {0.f, 0.f, 0.f, 0.f};   // path tile 0 (paths 0-15)
    f32x4 cv1 = {0.f, 0.f, 0.f, 0.f};   // path tile 1 (paths 16-31)
    float Slog_prev = 0.f, dS_prev = 0.f, disc1_prev = 1.f, t0_prev = 0.f;
    int   idx_prev = 0;
    bool  im_prev  = false;

    const float* zrow  = z   + (size_t)gpath * NSTEP;
    const float* zzrow = zzg + (size_t)gpath * NSTEP;

    const int p1p = tid >> 4;            // P1: path this thread computes (0..31)
    const int kc1 = tid & 15;            // P1: k-chunk (== col)

    __syncthreads();

    auto hedge_step = [&]() {
        if (hm >= idx_prev) {
            const float slp0 = __shfl(Slog_prev, col);
            const float slp1 = __shfl(Slog_prev, 16 + col);
            const float* Wp = WH1f + (hm * 4 + quad) * 36;
            U8 b0f, b1f;
#pragma unroll
            for (int hh = 0; hh < 2; hh++) {
                const float4 wt4 = *reinterpret_cast<const float4*>(Wp + hh * 4);
                const float4 ws4 = *reinterpret_cast<const float4*>(Wp + 8 + hh * 4);
                const float4 bb4 = *reinterpret_cast<const float4*>(Wp + 16 + hh * 4);
                const float c0 = bb4.x + t0_prev * wt4.x;
                const float c1 = bb4.y + t0_prev * wt4.y;
                const float c2 = bb4.z + t0_prev * wt4.z;
                const float c3 = bb4.w + t0_prev * wt4.w;
                (&b0f.u.x)[2 * hh]     = pk2(fmaxf(c0 + slp0 * ws4.x, 0.f), fmaxf(c1 + slp0 * ws4.y, 0.f));
                (&b0f.u.x)[2 * hh + 1] = pk2(fmaxf(c2 + slp0 * ws4.z, 0.f), fmaxf(c3 + slp0 * ws4.w, 0.f));
                (&b1f.u.x)[2 * hh]     = pk2(fmaxf(c0 + slp1 * ws4.x, 0.f), fmaxf(c1 + slp1 * ws4.y, 0.f));
                (&b1f.u.x)[2 * hh + 1] = pk2(fmaxf(c2 + slp1 * ws4.z, 0.f), fmaxf(c3 + slp1 * ws4.w, 0.f));
            }
            const f32x4 z4 = {0.f, 0.f, 0.f, 0.f};
            const f32x4 D0 = __builtin_amdgcn_mfma_f32_16x16x32_bf16(Ah, b0f.v, z4, 0, 0, 0);
            const f32x4 D1 = __builtin_amdgcn_mfma_f32_16x16x32_bf16(Ah, b1f.v, z4, 0, 0, 0);
            const float ds0 = __shfl(dS_prev, col);
            const float ds1 = __shfl(dS_prev, 16 + col);
#pragma unroll
            for (int r = 0; r < 4; r++) {
                cv0[r] += sp(D0[r] + b2h[r]) * ds0;
                cv1[r] += sp(D1[r] + b2h[r]) * ds1;
            }
            if (im_prev && hm == idx_prev) {
                const float Sp0 = __shfl(S, col);
                const float Sp1 = __shfl(S, 16 + col);
                float st[4], sq[4];
#pragma unroll
                for (int r = 0; r < 4; r++) {
                    const float p0 = disc1_prev * fmaxf(Sp0 - Ka[r], 0.f) - cv0[r];
                    const float p1 = disc1_prev * fmaxf(Sp1 - Ka[r], 0.f) - cv1[r];
                    st[r] = p0 + p1;
                    sq[r] = p0 * p0 + p1 * p1;
                }
#pragma unroll
                for (int o = 1; o <= 8; o <<= 1) {
#pragma unroll
                    for (int r = 0; r < 4; r++) {
                        st[r] += __shfl_xor(st[r], o);
                        sq[r] += __shfl_xor(sq[r], o);
                    }
                }
                if (col == 0) {
#pragma unroll
                    for (int r = 0; r < 4; r++) {
                        const int s = stile * 16 + quad * 4 + r;
                        if (s < 21) { PSs[s] = st[r]; PSq[s] = sq[r]; }
                    }
                }
            }
        }
    };

    auto ps_reduce = [&]() {
        if (w == 0 && im_prev) {
            const int s = lane & 31;
            if (s < 21) {
                const float val = (lane >= 32) ? PSq[s] : PSs[s];
                float* dst = (lane >= 32) ? psq : psum;
                dst[(idx_prev * 21 + s) * NGROUP + blockIdx.x] = val;
            }
        }
    };

    for (int i = 0; i < NSTEP; i++) {
        const float zi  = zrow[i];
        const float zzi = zzrow[i];
        const float4 sa = STa[i];
        const float4 sb = STb[i];
        const float t0 = sa.x, h = sa.y, sqh = sa.z, disc0 = sa.w;
        const float disc1 = sb.x;
        const int   idx   = (int)sb.y;
        const bool  im    = (sb.z != 0.f);

        // ===== Region 1: P1 h1 chunk | lagged hedge | vd/vv (wave 7) ========
        {
            const float slp = __shfl(Slog, p1p);
            const float vp  = __shfl(V, p1p);
            const float* Wp = W1f + kc1 * 36;
            uint4 o;
#pragma unroll
            for (int hh = 0; hh < 2; hh++) {
                const float4 a4 = *reinterpret_cast<const float4*>(Wp + hh * 4);
                const float4 b4 = *reinterpret_cast<const float4*>(Wp + 8 + hh * 4);
                const float4 c4 = *reinterpret_cast<const float4*>(Wp + 16 + hh * 4);
                const float4 d4 = *reinterpret_cast<const float4*>(Wp + 24 + hh * 4);
                const float x0 = fmaxf(d4.x + t0 * a4.x + slp * b4.x + vp * c4.x, 0.f);
                const float x1 = fmaxf(d4.y + t0 * a4.y + slp * b4.y + vp * c4.y, 0.f);
                const float x2 = fmaxf(d4.z + t0 * a4.z + slp * b4.z + vp * c4.z, 0.f);
                const float x3 = fmaxf(d4.w + t0 * a4.w + slp * b4.w + vp * c4.w, 0.f);
                (&o.x)[2 * hh]     = pk2(x0, x1);
                (&o.x)[2 * hh + 1] = pk2(x2, x3);
            }
            const int slot = kc1 ^ (p1p & 15);
            *reinterpret_cast<uint4*>(H1c + (p1p * 16 + slot) * 8) = o;
        }
        if (i > 0) hedge_step();
        if (w == 7) {                        // vd (lanes 0-31) / vv (32-63)
            const float* Wb = VW + ((lane >> 5) << 6);
            float a2 = 0.f;
#pragma unroll
            for (int q5 = 0; q5 < 5; q5++) {
                const float4 w1 = *reinterpret_cast<const float4*>(Wb + 4 * q5);
                const float4 b1 = *reinterpret_cast<const float4*>(Wb + 20 + 4 * q5);
                const float4 w2 = *reinterpret_cast<const float4*>(Wb + 40 + 4 * q5);
                a2 += fmaxf(V * w1.x + b1.x, 0.f) * w2.x;
                a2 += fmaxf(V * w1.y + b1.y, 0.f) * w2.y;
                a2 += fmaxf(V * w1.z + b1.z, 0.f) * w2.z;
                a2 += fmaxf(V * w1.w + b1.w, 0.f) * w2.w;
            }
            if (lane < 32) VDl[i & 1][pidx] = a2;
            else           VVl[i & 1][pidx] = a2;
        }
        __syncthreads();

        // ===== Region 2: main MFMA (waves 0-6) | PS global write ============
        if (w < 7) {
            f32x4 d0 = {0.f, 0.f, 0.f, 0.f};
            f32x4 d1 = {0.f, 0.f, 0.f, 0.f};
            const int rb0 = col * 16, rb1 = (16 + col) * 16;
#pragma unroll
            for (int c = 0; c < 4; c++) {
                const int slot = (4 * c + quad) ^ col;
                const bf16x8 b0 = *reinterpret_cast<const bf16x8*>(H1c + (rb0 + slot) * 8);
                const bf16x8 b1 = *reinterpret_cast<const bf16x8*>(H1c + (rb1 + slot) * 8);
                d0 = __builtin_amdgcn_mfma_f32_16x16x32_bf16(Af[c], b0, d0, 0, 0, 0);
                d1 = __builtin_amdgcn_mfma_f32_16x16x32_bf16(Af[c], b1, d1, 0, 0, 0);
            }
            const int j0 = w * 16 + quad * 4;
            const float4 b2a = *reinterpret_cast<const float4*>(B2T + j0);
            const float4 w3a = *reinterpret_cast<const float4*>(W3T + j0);
            float acc0 = fmaxf(d0[0] + b2a.x, 0.f) * w3a.x
                       + fmaxf(d0[1] + b2a.y, 0.f) * w3a.y
                       + fmaxf(d0[2] + b2a.z, 0.f) * w3a.z
                       + fmaxf(d0[3] + b2a.w, 0.f) * w3a.w;
            float acc1 = fmaxf(d1[0] + b2a.x, 0.f) * w3a.x
                       + fmaxf(d1[1] + b2a.y, 0.f) * w3a.y
                       + fmaxf(d1[2] + b2a.z, 0.f) * w3a.z
                       + fmaxf(d1[3] + b2a.w, 0.f) * w3a.w;
            acc0 += __shfl_xor(acc0, 16);  acc0 += __shfl_xor(acc0, 32);
            acc1 += __shfl_xor(acc1, 16);  acc1 += __shfl_xor(acc1, 32);
            if (quad == 0) {
                RED[w][col]      = acc0;
                RED[w][16 + col] = acc1;
            }
        }
        ps_reduce();
        __syncthreads();

        // ===== Region 3: SDE tail (per-path, mirrored in both lane halves) ==
        {
            float pout = RED[0][pidx] + RED[1][pidx] + RED[2][pidx] + RED[3][pidx]
                       + RED[4][pidx] + RED[5][pidx] + RED[6][pidx] + RED[7][pidx];
            const float pd = sp(pout + b3);
            const float vdv = VDl[i & 1][pidx] + VW[124];
            const float vvv = sp(VVl[i & 1][pidx] + VW[125]);
            const float dW = sqh * zi;
            const float dB = rho_t * dW + srho * sqh * zzi;
            const float Vn = V + vdv * h + vvv * dB;
            const float drift   = rate - 0.5f * pd * pd;
            const float diff    = pd * dW;
            const float drift_c = 1.f + fabsf(drift) * sqh;
            const float diff_c  = 1.f + fabsf(pd) * sqh;
            const float Sln = Slog + __fdividef(drift * h, drift_c) + __fdividef(diff, diff_c);
            const float Sn  = __expf(Sln);
            const float dS  = disc1 * Sn - disc0 * S;
            Slog_prev = Slog; dS_prev = dS; disc1_prev = disc1; t0_prev = t0;
            idx_prev = idx; im_prev = im;
            Slog = Sln; S = Sn; V = Vn;
        }
    }

    // ---- epilogue: step-95 hedge + final flush -----------------------------
    hedge_step();
    __syncthreads();
    ps_reduce();

    // ---- fused finalize: last block computes mean/var ----------------------
    __threadfence();
    __syncthreads();
    if (tid == 0) lastv = atomicAdd(cnt, 1u);
    __syncthreads();
    if (lastv == NGROUP - 1) {
        __threadfence();
        const int t   = tid >> 2;       // 0..127
        const int sub = tid & 3;
        if (t < NPAIR) {
            const float* ps = psum + t * NGROUP + sub * 128;
            const float* pq = psq  + t * NGROUP + sub * 128;
            float s = 0.f, q = 0.f;
#pragma unroll 4
            for (int b = 0; b < 128; b++) { s += ps[b]; q += pq[b]; }
            s += __shfl_xor(s, 1);  s += __shfl_xor(s, 2);
            q += __shfl_xor(q, 1);  q += __shfl_xor(q, 2);
            if (sub == 0) {
                const float mean = s * (1.0f / (float)MC);
                const float var  = (q - (float)MC * mean * mean) * (1.0f / (float)(MC - 1));
                out[t]         = mean;
                out[NPAIR + t] = var;
            }
        }
    }
}

extern "C" void kernel_launch(void* const* d_in, const int* in_sizes, int n_in,
                              void* d_out, int out_size, void* d_ws, size_t ws_size,
                              hipStream_t stream)
{
    const float* S0    = (const float*)d_in[0];
    const float* rate  = (const float*)d_in[1];
    const float* z     = (const float*)d_in[2];
    const float* zz    = (const float*)d_in[3];
    const float* strikes = (const float*)d_in[5];
    const float* v0    = (const float*)d_in[6];
    const float* rho   = (const float*)d_in[7];
    const float* svW1  = (const float*)d_in[8];
    const float* svb1  = (const float*)d_in[9];
    const float* svW2  = (const float*)d_in[10];
    const float* svb2  = (const float*)d_in[11];
    const float* svW3  = (const float*)d_in[12];
    const float* svb3  = (const float*)d_in[13];
    const float* vhW1  = (const float*)d_in[14];
    const float* vhb1  = (const float*)d_in[15];
    const float* vhW2  = (const float*)d_in[16];
    const float* vhb2  = (const float*)d_in[17];
    const float* vdW1  = (const float*)d_in[18];
    const float* vdb1  = (const float*)d_in[19];
    const float* vdW2  = (const float*)d_in[20];
    const float* vdb2  = (const float*)d_in[21];
    const float* vvW1  = (const float*)d_in[22];
    const float* vvb1  = (const float*)d_in[23];
    const float* vvW2  = (const float*)d_in[24];
    const float* vvb2  = (const float*)d_in[25];
    const int*   mats  = (const int*)d_in[26];

    float*    psum = (float*)d_ws;                       // [NPAIR][NGROUP]
    float*    psq  = psum + NPAIR * NGROUP;              // [NPAIR][NGROUP]
    unsigned* cnt  = (unsigned*)(psq + NPAIR * NGROUP);  // 1 counter

    hipMemsetAsync((void*)cnt, 0, sizeof(unsigned), stream);

    hipLaunchKernelGGL(lsv_sim, dim3(NGROUP), dim3(BLOCK), 0, stream,
                       S0, rate, z, zz, strikes, v0, rho,
                       svW1, svb1, svW2, svb2, svW3, svb3,
                       vhW1, vhb1, vhW2, vhb2,
                       vdW1, vdb1, vdW2, vdb2,
                       vvW1, vvb1, vvW2, vvb2,
                       mats, psum, psq, cnt, (float*)d_out);
}

// Round 8
// 482.251 us; speedup vs baseline: 1.0115x; 1.0115x over previous
//
#include <hip/hip_runtime.h>
#include <hip/hip_bf16.h>
#include <math.h>

// ---------------------------------------------------------------------------
// LSV Monte Carlo, round 8 = round 6 (best: 353us sim) + trims:
//  * per-step scalars (t0,h,sqrt,discounts,maturity idx/flag) from a 96-entry
//    LDS table staged once -- removes sqrt+2exp+search from every wave-step.
//  * vd/vv nets split across waves 12/13/14/15 (half-nets) instead of 14/15
//    doing whole nets -- halves the barrier straggler.
//  * separate finalize kernel (R7's fused-atomic version regressed).
// Structure: 256 blocks x 1024 threads, lane=path (64/block), 16 waves:
// wave w: main-GEMM j-group (w>>2 -> 2 16-j tiles), hedge (mat w>>2, strike
// slice w&3), MFMA A-operands = invariant weights in AGPRs, H1 bf16 chunks
// [kchunk][path][16B] (conflict-free), hedge lagged one step.
// ---------------------------------------------------------------------------

#define MC      16384
#define NSTEP   96
#define BLOCK   1024
#define NGROUP  256
#define NPAIR   84

typedef short bf16x8 __attribute__((ext_vector_type(8)));
typedef float f32x4  __attribute__((ext_vector_type(4)));

union U8 { uint4 u; bf16x8 v; };
union BF2U { __hip_bfloat162 b; unsigned u; };

__device__ __forceinline__ unsigned bf16rne(float x) {   // setup-time only
    unsigned u = __float_as_uint(x);
    return (u + 0x7FFFu + ((u >> 16) & 1u)) >> 16;
}
__device__ __forceinline__ unsigned pk2(float lo, float hi) {
    BF2U t; t.b = __float22bfloat162_rn(make_float2(lo, hi));
    return t.u;
}
__device__ __forceinline__ float sp(float x) {
    return fmaxf(x, 0.f) + __logf(1.f + __expf(-fabsf(x)));
}

__global__ __launch_bounds__(BLOCK, 4)
void lsv_sim(const float* __restrict__ S0p,   const float* __restrict__ ratep,
             const float* __restrict__ z,     const float* __restrict__ zzg,
             const float* __restrict__ strikesg,
             const float* __restrict__ v0p,   const float* __restrict__ rhop,
             const float* __restrict__ svW1,  const float* __restrict__ svb1,
             const float* __restrict__ svW2,  const float* __restrict__ svb2,
             const float* __restrict__ svW3,  const float* __restrict__ svb3,
             const float* __restrict__ vhW1,  const float* __restrict__ vhb1,
             const float* __restrict__ vhW2,  const float* __restrict__ vhb2,
             const float* __restrict__ vdW1,  const float* __restrict__ vdb1,
             const float* __restrict__ vdW2,  const float* __restrict__ vdb2,
             const float* __restrict__ vvW1,  const float* __restrict__ vvb1,
             const float* __restrict__ vvW2,  const float* __restrict__ vvb2,
             const int*   __restrict__ mats,
             float* __restrict__ psum, float* __restrict__ psq)
{
    __shared__ __align__(16) unsigned short H1c[16 * 64 * 8]; // 16 KB [kchunk][path][8]
    __shared__ __align__(16) float W1f[16 * 32];              // 2 KB
    __shared__ __align__(16) float WH1f[16 * 32];             // 2 KB
    __shared__ __align__(16) float B2T[128], W3T[128];        // 1 KB
    __shared__ __align__(16) float4 STa[96], STb[96];         // 3 KB per-step scalars
    __shared__ float RED[64 * 4];                             // 1 KB [path][jg]
    __shared__ float VDa[2][64], VDb[2][64];                  // 1 KB vd partials
    __shared__ float VVa[2][64], VVb[2][64];                  // 1 KB vv partials
    __shared__ float PSs[4][32], PSq[4][32];                  // 1 KB
    __shared__ float VW[128];                                 // 512 B

    const int tid  = threadIdx.x;
    const int lane = tid & 63;
    const int w    = __builtin_amdgcn_readfirstlane(tid >> 6);
    const int quad = lane >> 4;
    const int col  = lane & 15;
    const int gpath = blockIdx.x * 64 + lane;

    const int pt = w & 3;      // path tile (both GEMMs)
    const int jg = w >> 2;     // main: j-group 0..3 (j-tiles 2jg, 2jg+1)
    const int hm = w >> 2;     // hedge: maturity

    // ---- stage LDS tables --------------------------------------------------
    for (int e = tid; e < 128; e += BLOCK) {
        float v = 0.f;
        if      (e < 20)             v = vdW1[e];
        else if (e < 40)             v = vdb1[e - 20];
        else if (e < 60)             v = vdW2[e - 40];
        else if (e >= 64 && e < 84)  v = vvW1[e - 64];
        else if (e >= 84 && e < 104) v = vvb1[e - 84];
        else if (e >= 104 && e < 124)v = vvW2[e - 104];
        else if (e == 124)           v = vdb2[0];
        else if (e == 125)           v = vvb2[0];
        VW[e] = v;
        B2T[e] = (e < 100) ? svb2[e] : 0.f;
        W3T[e] = (e < 100) ? svW3[e] : 0.f;
    }
    for (int e = tid; e < 512; e += BLOCK) {       // W1f
        const int kc2 = e >> 5, r5 = e & 31, grp = r5 >> 3, kk = kc2 * 8 + (r5 & 7);
        float v = 0.f;
        if (kk < 100) v = (grp == 0) ? svW1[kk] : (grp == 1) ? svW1[100 + kk]
                        : (grp == 2) ? svW1[200 + kk] : svb1[kk];
        W1f[e] = v;
    }
    for (int e = tid; e < 512; e += BLOCK) {       // WH1f
        const int hq = e >> 5, r5 = e & 31, grp = r5 >> 3;
        const int hmm = hq >> 2, qq = hq & 3;
        const int j = qq * 8 + (r5 & 7);
        float v = 0.f;
        if (j < 20 && grp < 3)
            v = (grp == 0) ? vhW1[hmm * 40 + j] : (grp == 1) ? vhW1[hmm * 40 + 20 + j]
                                                : vhb1[hmm * 20 + j];
        WH1f[e] = v;
    }
    if (tid < 96) {                                // per-step scalar table
        const int i = tid;
        const float t0 = (float)i       * (1.f / 365.f);
        const float t1 = (float)(i + 1) * (1.f / 365.f);
        const float hh = t1 - t0;
        const float rr = ratep[0];
        const int  day = i + 1;
        const int  mm0 = mats[0], mm1 = mats[1], mm2 = mats[2], mm3 = mats[3];
        const int  idx = (day > mm0) + (day > mm1) + (day > mm2);
        const int  mday = (idx == 0) ? mm0 : (idx == 1) ? mm1 : (idx == 2) ? mm2 : mm3;
        STa[i] = make_float4(t0, hh, sqrtf(hh), __expf(-rr * t0));
        STb[i] = make_float4(__expf(-rr * t1), (float)idx, (day == mday) ? 1.f : 0.f, 0.f);
    }

    // ---- uniform setup -----------------------------------------------------
    const float rate  = ratep[0];
    const float S0    = S0p[0];
    const float rho_t = tanhf(rhop[0]);
    const float srho  = sqrtf(1.f - rho_t * rho_t);
    const float b3    = svb3[0];

    // ---- invariant A-fragments (weights) -> AGPRs --------------------------
    // main: A[m=j][k], j = (2jg+t)*16 + col, k = 32c + 8quad + e
    bf16x8 Af[4][2];
#pragma unroll
    for (int c = 0; c < 4; c++)
#pragma unroll
        for (int t = 0; t < 2; t++) {
            U8 tt;
#pragma unroll
            for (int e2 = 0; e2 < 4; e2++) {
                const int k0 = 32 * c + 8 * quad + 2 * e2;
                const int j  = (2 * jg + t) * 16 + col;
                const float v0 = (k0     < 100 && j < 100) ? svW2[k0 * 100 + j]       : 0.f;
                const float v1 = (k0 + 1 < 100 && j < 100) ? svW2[(k0 + 1) * 100 + j] : 0.f;
                (&tt.u.x)[e2] = bf16rne(v0) | (bf16rne(v1) << 16);
            }
            Af[c][t] = tt.v;
        }
    // hedge: A[m=s][k=j], s = st*16 + col, j = 8quad + e
    bf16x8 Ah[2];
#pragma unroll
    for (int st = 0; st < 2; st++) {
        U8 tt;
#pragma unroll
        for (int e2 = 0; e2 < 4; e2++) {
            const int j0 = 8 * quad + 2 * e2, j1 = j0 + 1;
            const int s  = st * 16 + col;
            const float v0 = (j0 < 20 && s < 21) ? vhW2[hm * 420 + j0 * 21 + s] : 0.f;
            const float v1 = (j1 < 20 && s < 21) ? vhW2[hm * 420 + j1 * 21 + s] : 0.f;
            (&tt.u.x)[e2] = bf16rne(v0) | (bf16rne(v1) << 16);
        }
        Ah[st] = tt.v;
    }
    // hedge per-lane D-row constants: s0 = quad*4+r (<16), s1 = 16+quad*4+r
    float b2h0[4], b2h1[4], K0a[4], K1a[4];
#pragma unroll
    for (int r = 0; r < 4; r++) {
        const int s0 = quad * 4 + r, s1 = 16 + quad * 4 + r;
        b2h0[r] = vhb2[hm * 21 + s0];
        K0a[r]  = strikesg[s0];
        b2h1[r] = (s1 < 21) ? vhb2[hm * 21 + s1] : 0.f;
        K1a[r]  = (s1 < 21) ? strikesg[s1] : 1e30f;
    }

    // ---- per-path state (lane = path, redundant across waves) --------------
    float Slog = __logf(S0);
    float S    = __expf(Slog);
    float V    = (1.f / (1.f + __expf(-v0p[0]))) * 0.5f;
    f32x4 cv0 = {0.f, 0.f, 0.f, 0.f};
    f32x4 cv1 = {0.f, 0.f, 0.f, 0.f};
    float Slog_prev = 0.f, dS_prev = 0.f, disc1_prev = 1.f, t0_prev = 0.f;
    int   idx_prev = 0;
    bool  im_prev  = false;

    const float* zrow  = z   + (size_t)gpath * NSTEP;
    const float* zzrow = zzg + (size_t)gpath * NSTEP;

    const int path = pt * 16 + col;        // P1/B-frag path of this thread
    const int kc   = jg * 4 + quad;        // P1 k-chunk of this thread

    __syncthreads();

    auto hedge_step = [&]() {
        if (hm >= idx_prev) {
            const float slp = __shfl(Slog_prev, path);
            U8 b;
#pragma unroll
            for (int hh = 0; hh < 2; hh++) {
                const float* Wp = WH1f + (hm * 4 + quad) * 32 + hh * 4;
                const float4 wt4 = *reinterpret_cast<const float4*>(Wp);
                const float4 ws4 = *reinterpret_cast<const float4*>(Wp + 8);
                const float4 bb4 = *reinterpret_cast<const float4*>(Wp + 16);
                const float x0 = fmaxf(bb4.x + t0_prev * wt4.x + slp * ws4.x, 0.f);
                const float x1 = fmaxf(bb4.y + t0_prev * wt4.y + slp * ws4.y, 0.f);
                const float x2 = fmaxf(bb4.z + t0_prev * wt4.z + slp * ws4.z, 0.f);
                const float x3 = fmaxf(bb4.w + t0_prev * wt4.w + slp * ws4.w, 0.f);
                (&b.u.x)[2 * hh]     = pk2(x0, x1);
                (&b.u.x)[2 * hh + 1] = pk2(x2, x3);
            }
            const f32x4 z4 = {0.f, 0.f, 0.f, 0.f};
            const f32x4 D0 = __builtin_amdgcn_mfma_f32_16x16x32_bf16(Ah[0], b.v, z4, 0, 0, 0);
            const f32x4 D1 = __builtin_amdgcn_mfma_f32_16x16x32_bf16(Ah[1], b.v, z4, 0, 0, 0);
            const float dsP = __shfl(dS_prev, path);
#pragma unroll
            for (int r = 0; r < 4; r++) {
                cv0[r] += sp(D0[r] + b2h0[r]) * dsP;
                cv1[r] += sp(D1[r] + b2h1[r]) * dsP;
            }
            if (im_prev && hm == idx_prev) {
                const float Sp = __shfl(S, path);
                float p0[4], q0[4], p1[4], q1[4];
#pragma unroll
                for (int r = 0; r < 4; r++) {
                    p0[r] = disc1_prev * fmaxf(Sp - K0a[r], 0.f) - cv0[r];
                    p1[r] = disc1_prev * fmaxf(Sp - K1a[r], 0.f) - cv1[r];
                    q0[r] = p0[r] * p0[r];
                    q1[r] = p1[r] * p1[r];
                }
#pragma unroll
                for (int o = 1; o <= 8; o <<= 1) {
#pragma unroll
                    for (int r = 0; r < 4; r++) {
                        p0[r] += __shfl_xor(p0[r], o);
                        q0[r] += __shfl_xor(q0[r], o);
                        p1[r] += __shfl_xor(p1[r], o);
                        q1[r] += __shfl_xor(q1[r], o);
                    }
                }
                if (col == 0) {
#pragma unroll
                    for (int r = 0; r < 4; r++) {
                        const int s0 = quad * 4 + r, s1 = 16 + quad * 4 + r;
                        PSs[pt][s0] = p0[r];  PSq[pt][s0] = q0[r];
                        if (s1 < 21) { PSs[pt][s1] = p1[r];  PSq[pt][s1] = q1[r]; }
                    }
                }
            }
        }
    };

    auto ps_reduce = [&]() {
        if (w == 0 && im_prev) {
            const int s = lane & 31;
            if (s < 21) {
                const float* src = (lane >= 32) ? &PSq[0][0] : &PSs[0][0];
                const float acc = src[s] + src[32 + s] + src[64 + s] + src[96 + s];
                float* dst = (lane >= 32) ? psq : psum;
                dst[(idx_prev * 21 + s) * NGROUP + blockIdx.x] = acc;
            }
        }
    };

    for (int i = 0; i < NSTEP; i++) {
        const float zi  = zrow[i];
        const float zzi = zzrow[i];
        const float4 sa = STa[i];
        const float4 sb = STb[i];
        const float t0 = sa.x, h = sa.y, sqh = sa.z, disc0 = sa.w;
        const float disc1 = sb.x;
        const int   idx   = (int)sb.y;
        const bool  im    = (sb.z != 0.f);

        // ===== Region 1: P1 h1 chunk | lagged hedge | vd/vv half-nets =======
        {
            const float slp = __shfl(Slog, path);
            const float vp  = __shfl(V, path);
            const float* Wp = W1f + kc * 32;
            uint4 o;
#pragma unroll
            for (int hh = 0; hh < 2; hh++) {
                const float4 a4 = *reinterpret_cast<const float4*>(Wp + hh * 4);
                const float4 b4 = *reinterpret_cast<const float4*>(Wp + 8 + hh * 4);
                const float4 c4 = *reinterpret_cast<const float4*>(Wp + 16 + hh * 4);
                const float4 d4 = *reinterpret_cast<const float4*>(Wp + 24 + hh * 4);
                const float x0 = fmaxf(d4.x + t0 * a4.x + slp * b4.x + vp * c4.x, 0.f);
                const float x1 = fmaxf(d4.y + t0 * a4.y + slp * b4.y + vp * c4.y, 0.f);
                const float x2 = fmaxf(d4.z + t0 * a4.z + slp * b4.z + vp * c4.z, 0.f);
                const float x3 = fmaxf(d4.w + t0 * a4.w + slp * b4.w + vp * c4.w, 0.f);
                (&o.x)[2 * hh]     = pk2(x0, x1);
                (&o.x)[2 * hh + 1] = pk2(x2, x3);
            }
            *reinterpret_cast<uint4*>(H1c + (kc * 64 + path) * 8) = o;
        }
        if (i > 0) hedge_step();
        if (w == 12) {            // vd hidden 0-7
            float a2 = 0.f;
#pragma unroll
            for (int q5 = 0; q5 < 2; q5++) {
                const float4 w1 = *reinterpret_cast<const float4*>(VW + 4 * q5);
                const float4 b1 = *reinterpret_cast<const float4*>(VW + 20 + 4 * q5);
                const float4 w2 = *reinterpret_cast<const float4*>(VW + 40 + 4 * q5);
                a2 += fmaxf(V * w1.x + b1.x, 0.f) * w2.x;
                a2 += fmaxf(V * w1.y + b1.y, 0.f) * w2.y;
                a2 += fmaxf(V * w1.z + b1.z, 0.f) * w2.z;
                a2 += fmaxf(V * w1.w + b1.w, 0.f) * w2.w;
            }
            VDa[i & 1][lane] = a2;
        } else if (w == 13) {     // vd hidden 8-19
            float a2 = 0.f;
#pragma unroll
            for (int q5 = 2; q5 < 5; q5++) {
                const float4 w1 = *reinterpret_cast<const float4*>(VW + 4 * q5);
                const float4 b1 = *reinterpret_cast<const float4*>(VW + 20 + 4 * q5);
                const float4 w2 = *reinterpret_cast<const float4*>(VW + 40 + 4 * q5);
                a2 += fmaxf(V * w1.x + b1.x, 0.f) * w2.x;
                a2 += fmaxf(V * w1.y + b1.y, 0.f) * w2.y;
                a2 += fmaxf(V * w1.z + b1.z, 0.f) * w2.z;
                a2 += fmaxf(V * w1.w + b1.w, 0.f) * w2.w;
            }
            VDb[i & 1][lane] = a2;
        } else if (w == 14) {     // vv hidden 0-7
            float a2 = 0.f;
#pragma unroll
            for (int q5 = 0; q5 < 2; q5++) {
                const float4 w1 = *reinterpret_cast<const float4*>(VW + 64 + 4 * q5);
                const float4 b1 = *reinterpret_cast<const float4*>(VW + 84 + 4 * q5);
                const float4 w2 = *reinterpret_cast<const float4*>(VW + 104 + 4 * q5);
                a2 += fmaxf(V * w1.x + b1.x, 0.f) * w2.x;
                a2 += fmaxf(V * w1.y + b1.y, 0.f) * w2.y;
                a2 += fmaxf(V * w1.z + b1.z, 0.f) * w2.z;
                a2 += fmaxf(V * w1.w + b1.w, 0.f) * w2.w;
            }
            VVa[i & 1][lane] = a2;
        } else if (w == 15) {     // vv hidden 8-19
            float a2 = 0.f;
#pragma unroll
            for (int q5 = 2; q5 < 5; q5++) {
                const float4 w1 = *reinterpret_cast<const float4*>(VW + 64 + 4 * q5);
                const float4 b1 = *reinterpret_cast<const float4*>(VW + 84 + 4 * q5);
                const float4 w2 = *reinterpret_cast<const float4*>(VW + 104 + 4 * q5);
                a2 += fmaxf(V * w1.x + b1.x, 0.f) * w2.x;
                a2 += fmaxf(V * w1.y + b1.y, 0.f) * w2.y;
                a2 += fmaxf(V * w1.z + b1.z, 0.f) * w2.z;
                a2 += fmaxf(V * w1.w + b1.w, 0.f) * w2.w;
            }
            VVb[i & 1][lane] = a2;
        }
        __syncthreads();

        // ===== Region 2: main MFMA (A=W2T inv, B=h1) + per-lane epilogue ====
        {
            f32x4 d0 = {0.f, 0.f, 0.f, 0.f};
            f32x4 d1 = {0.f, 0.f, 0.f, 0.f};
#pragma unroll
            for (int c = 0; c < 4; c++) {
                const bf16x8 b = *reinterpret_cast<const bf16x8*>(
                    H1c + ((quad + 4 * c) * 64 + path) * 8);
                d0 = __builtin_amdgcn_mfma_f32_16x16x32_bf16(Af[c][0], b, d0, 0, 0, 0);
                d1 = __builtin_amdgcn_mfma_f32_16x16x32_bf16(Af[c][1], b, d1, 0, 0, 0);
            }
            const int j0 = (2 * jg) * 16 + quad * 4;
            const float4 b2a = *reinterpret_cast<const float4*>(B2T + j0);
            const float4 w3a = *reinterpret_cast<const float4*>(W3T + j0);
            const float4 b2b = *reinterpret_cast<const float4*>(B2T + j0 + 16);
            const float4 w3b = *reinterpret_cast<const float4*>(W3T + j0 + 16);
            float acc = fmaxf(d0[0] + b2a.x, 0.f) * w3a.x
                      + fmaxf(d0[1] + b2a.y, 0.f) * w3a.y
                      + fmaxf(d0[2] + b2a.z, 0.f) * w3a.z
                      + fmaxf(d0[3] + b2a.w, 0.f) * w3a.w
                      + fmaxf(d1[0] + b2b.x, 0.f) * w3b.x
                      + fmaxf(d1[1] + b2b.y, 0.f) * w3b.y
                      + fmaxf(d1[2] + b2b.z, 0.f) * w3b.z
                      + fmaxf(d1[3] + b2b.w, 0.f) * w3b.w;
            acc += __shfl_xor(acc, 16);
            acc += __shfl_xor(acc, 32);
            if (quad == 0)
                RED[path * 4 + jg] = acc;
        }
        ps_reduce();
        __syncthreads();

        // ===== Region 3: SDE tail (redundant per wave, state in regs) =======
        {
            const float4 rr = *reinterpret_cast<const float4*>(RED + lane * 4);
            const float pout = (rr.x + rr.y) + (rr.z + rr.w);
            const float pd = sp(pout + b3);
            const float vdv = VDa[i & 1][lane] + VDb[i & 1][lane] + VW[124];
            const float vvv = sp(VVa[i & 1][lane] + VVb[i & 1][lane] + VW[125]);
            const float dW = sqh * zi;
            const float dB = rho_t * dW + srho * sqh * zzi;
            const float Vn = V + vdv * h + vvv * dB;
            const float drift   = rate - 0.5f * pd * pd;
            const float diff    = pd * dW;
            const float drift_c = 1.f + fabsf(drift) * sqh;
            const float diff_c  = 1.f + fabsf(pd) * sqh;
            const float Sln = Slog + __fdividef(drift * h, drift_c) + __fdividef(diff, diff_c);
            const float Sn  = __expf(Sln);
            const float dS  = disc1 * Sn - disc0 * S;
            Slog_prev = Slog; dS_prev = dS; disc1_prev = disc1; t0_prev = t0;
            idx_prev = idx; im_prev = im;
            Slog = Sln; S = Sn; V = Vn;
        }
    }

    hedge_step();
    __syncthreads();
    ps_reduce();
}

__global__ void lsv_finalize(const float* __restrict__ psum,
                             const float* __restrict__ psq,
                             float* __restrict__ out)
{
    const int t = blockIdx.x * blockDim.x + threadIdx.x;
    if (t >= NPAIR) return;
    float s = 0.f, q = 0.f;
    for (int b = 0; b < NGROUP; b++) {
        s += psum[t * NGROUP + b];
        q += psq [t * NGROUP + b];
    }
    const float mean = s * (1.0f / (float)MC);
    const float var  = (q - (float)MC * mean * mean) * (1.0f / (float)(MC - 1));
    out[t]         = mean;
    out[NPAIR + t] = var;
}

extern "C" void kernel_launch(void* const* d_in, const int* in_sizes, int n_in,
                              void* d_out, int out_size, void* d_ws, size_t ws_size,
                              hipStream_t stream)
{
    const float* S0    = (const float*)d_in[0];
    const float* rate  = (const float*)d_in[1];
    const float* z     = (const float*)d_in[2];
    const float* zz    = (const float*)d_in[3];
    const float* strikes = (const float*)d_in[5];
    const float* v0    = (const float*)d_in[6];
    const float* rho   = (const float*)d_in[7];
    const float* svW1  = (const float*)d_in[8];
    const float* svb1  = (const float*)d_in[9];
    const float* svW2  = (const float*)d_in[10];
    const float* svb2  = (const float*)d_in[11];
    const float* svW3  = (const float*)d_in[12];
    const float* svb3  = (const float*)d_in[13];
    const float* vhW1  = (const float*)d_in[14];
    const float* vhb1  = (const float*)d_in[15];
    const float* vhW2  = (const float*)d_in[16];
    const float* vhb2  = (const float*)d_in[17];
    const float* vdW1  = (const float*)d_in[18];
    const float* vdb1  = (const float*)d_in[19];
    const float* vdW2  = (const float*)d_in[20];
    const float* vdb2  = (const float*)d_in[21];
    const float* vvW1  = (const float*)d_in[22];
    const float* vvb1  = (const float*)d_in[23];
    const float* vvW2  = (const float*)d_in[24];
    const float* vvb2  = (const float*)d_in[25];
    const int*   mats  = (const int*)d_in[26];

    float* psum = (float*)d_ws;
    float* psq  = psum + NPAIR * NGROUP;

    hipLaunchKernelGGL(lsv_sim, dim3(NGROUP), dim3(BLOCK), 0, stream,
                       S0, rate, z, zz, strikes, v0, rho,
                       svW1, svb1, svW2, svb2, svW3, svb3,
                       vhW1, vhb1, vhW2, vhb2,
                       vdW1, vdb1, vdW2, vdb2,
                       vvW1, vvb1, vvW2, vvb2,
                       mats, psum, psq);

    hipLaunchKernelGGL(lsv_finalize, dim3(1), dim3(128), 0, stream,
                       psum, psq, (float*)d_out);
}

// Round 9
// 439.434 us; speedup vs baseline: 1.1101x; 1.0974x over previous
//
#include <hip/hip_runtime.h>
#include <hip/hip_bf16.h>
#include <math.h>

// ---------------------------------------------------------------------------
// LSV Monte Carlo, round 9 = round 6 (best: 353us sim / 434us total) with ONE
// register-neutral change: fast softplus log(1+exp(x)) (safe: |x| << 88 here),
// replacing the 7-op stable form. R7 (8-wave blocks) and R8 (LDS scalar table
// + vd/vv split) both regressed via scratch spill / scheduling -- reverted.
// Structure: 256 blocks x 1024 threads, lane=path (64/block), 16 waves:
// wave w: main-GEMM j-group (w>>2 -> 2 16-j tiles), hedge (mat w>>2, strike
// slice quad-rows), MFMA A-operands = invariant weights in AGPRs, H1 bf16
// chunks [kchunk][path][16B] (conflict-free), hedge lagged one step.
// ---------------------------------------------------------------------------

#define MC      16384
#define NSTEP   96
#define BLOCK   1024
#define NGROUP  256
#define NPAIR   84

typedef short bf16x8 __attribute__((ext_vector_type(8)));
typedef float f32x4  __attribute__((ext_vector_type(4)));

union U8 { uint4 u; bf16x8 v; };
union BF2U { __hip_bfloat162 b; unsigned u; };

__device__ __forceinline__ unsigned bf16rne(float x) {   // setup-time only
    unsigned u = __float_as_uint(x);
    return (u + 0x7FFFu + ((u >> 16) & 1u)) >> 16;
}
__device__ __forceinline__ unsigned pk2(float lo, float hi) {
    BF2U t; t.b = __float22bfloat162_rn(make_float2(lo, hi));
    return t.u;
}
// fast softplus: inputs here are O(1)-O(10), far from fp32 exp overflow (~88),
// matches jax.nn.softplus to ~1e-6 in this range. 3 ops vs 7.
__device__ __forceinline__ float sp(float x) {
    return __logf(1.f + __expf(x));
}

__global__ __launch_bounds__(BLOCK, 4)
void lsv_sim(const float* __restrict__ S0p,   const float* __restrict__ ratep,
             const float* __restrict__ z,     const float* __restrict__ zzg,
             const float* __restrict__ strikesg,
             const float* __restrict__ v0p,   const float* __restrict__ rhop,
             const float* __restrict__ svW1,  const float* __restrict__ svb1,
             const float* __restrict__ svW2,  const float* __restrict__ svb2,
             const float* __restrict__ svW3,  const float* __restrict__ svb3,
             const float* __restrict__ vhW1,  const float* __restrict__ vhb1,
             const float* __restrict__ vhW2,  const float* __restrict__ vhb2,
             const float* __restrict__ vdW1,  const float* __restrict__ vdb1,
             const float* __restrict__ vdW2,  const float* __restrict__ vdb2,
             const float* __restrict__ vvW1,  const float* __restrict__ vvb1,
             const float* __restrict__ vvW2,  const float* __restrict__ vvb2,
             const int*   __restrict__ mats,
             float* __restrict__ psum, float* __restrict__ psq)
{
    __shared__ __align__(16) unsigned short H1c[16 * 64 * 8]; // 16 KB [kchunk][path][8]
    __shared__ __align__(16) float W1f[16 * 32];              // 2 KB
    __shared__ __align__(16) float WH1f[16 * 32];             // 2 KB
    __shared__ __align__(16) float B2T[128], W3T[128];        // 1 KB
    __shared__ float RED[64 * 4];                             // 1 KB [path][jg]
    __shared__ float VDl[2][64], VVl[2][64];                  // 1 KB
    __shared__ float PSs[4][32], PSq[4][32];                  // 1 KB
    __shared__ float VW[128];                                 // 512 B

    const int tid  = threadIdx.x;
    const int lane = tid & 63;
    const int w    = __builtin_amdgcn_readfirstlane(tid >> 6);
    const int quad = lane >> 4;
    const int col  = lane & 15;
    const int gpath = blockIdx.x * 64 + lane;

    const int pt = w & 3;      // path tile (both GEMMs)
    const int jg = w >> 2;     // main: j-group 0..3 (j-tiles 2jg, 2jg+1)
    const int hm = w >> 2;     // hedge: maturity

    // ---- stage LDS tables --------------------------------------------------
    for (int e = tid; e < 128; e += BLOCK) {
        float v = 0.f;
        if      (e < 20)             v = vdW1[e];
        else if (e < 40)             v = vdb1[e - 20];
        else if (e < 60)             v = vdW2[e - 40];
        else if (e >= 64 && e < 84)  v = vvW1[e - 64];
        else if (e >= 84 && e < 104) v = vvb1[e - 84];
        else if (e >= 104 && e < 124)v = vvW2[e - 104];
        else if (e == 124)           v = vdb2[0];
        else if (e == 125)           v = vvb2[0];
        VW[e] = v;
        B2T[e] = (e < 100) ? svb2[e] : 0.f;
        W3T[e] = (e < 100) ? svW3[e] : 0.f;
    }
    for (int e = tid; e < 512; e += BLOCK) {       // W1f
        const int kc2 = e >> 5, r5 = e & 31, grp = r5 >> 3, kk = kc2 * 8 + (r5 & 7);
        float v = 0.f;
        if (kk < 100) v = (grp == 0) ? svW1[kk] : (grp == 1) ? svW1[100 + kk]
                        : (grp == 2) ? svW1[200 + kk] : svb1[kk];
        W1f[e] = v;
    }
    for (int e = tid; e < 512; e += BLOCK) {       // WH1f
        const int hq = e >> 5, r5 = e & 31, grp = r5 >> 3;
        const int hmm = hq >> 2, qq = hq & 3;
        const int j = qq * 8 + (r5 & 7);
        float v = 0.f;
        if (j < 20 && grp < 3)
            v = (grp == 0) ? vhW1[hmm * 40 + j] : (grp == 1) ? vhW1[hmm * 40 + 20 + j]
                                                : vhb1[hmm * 20 + j];
        WH1f[e] = v;
    }

    // ---- uniform setup -----------------------------------------------------
    const float rate  = ratep[0];
    const float S0    = S0p[0];
    const float rho_t = tanhf(rhop[0]);
    const float srho  = sqrtf(1.f - rho_t * rho_t);
    const float b3    = svb3[0];
    int matr[4];
#pragma unroll
    for (int k = 0; k < 4; k++) matr[k] = mats[k];

    // ---- invariant A-fragments (weights) -> AGPRs --------------------------
    // main: A[m=j][k], j = (2jg+t)*16 + col, k = 32c + 8quad + e
    bf16x8 Af[4][2];
#pragma unroll
    for (int c = 0; c < 4; c++)
#pragma unroll
        for (int t = 0; t < 2; t++) {
            U8 tt;
#pragma unroll
            for (int e2 = 0; e2 < 4; e2++) {
                const int k0 = 32 * c + 8 * quad + 2 * e2;
                const int j  = (2 * jg + t) * 16 + col;
                const float v0 = (k0     < 100 && j < 100) ? svW2[k0 * 100 + j]       : 0.f;
                const float v1 = (k0 + 1 < 100 && j < 100) ? svW2[(k0 + 1) * 100 + j] : 0.f;
                (&tt.u.x)[e2] = bf16rne(v0) | (bf16rne(v1) << 16);
            }
            Af[c][t] = tt.v;
        }
    // hedge: A[m=s][k=j], s = st*16 + col, j = 8quad + e
    bf16x8 Ah[2];
#pragma unroll
    for (int st = 0; st < 2; st++) {
        U8 tt;
#pragma unroll
        for (int e2 = 0; e2 < 4; e2++) {
            const int j0 = 8 * quad + 2 * e2, j1 = j0 + 1;
            const int s  = st * 16 + col;
            const float v0 = (j0 < 20 && s < 21) ? vhW2[hm * 420 + j0 * 21 + s] : 0.f;
            const float v1 = (j1 < 20 && s < 21) ? vhW2[hm * 420 + j1 * 21 + s] : 0.f;
            (&tt.u.x)[e2] = bf16rne(v0) | (bf16rne(v1) << 16);
        }
        Ah[st] = tt.v;
    }
    // hedge per-lane D-row constants: s0 = quad*4+r (<16), s1 = 16+quad*4+r
    float b2h0[4], b2h1[4], K0a[4], K1a[4];
#pragma unroll
    for (int r = 0; r < 4; r++) {
        const int s0 = quad * 4 + r, s1 = 16 + quad * 4 + r;
        b2h0[r] = vhb2[hm * 21 + s0];
        K0a[r]  = strikesg[s0];
        b2h1[r] = (s1 < 21) ? vhb2[hm * 21 + s1] : 0.f;
        K1a[r]  = (s1 < 21) ? strikesg[s1] : 1e30f;
    }

    // ---- per-path state (lane = path, redundant across waves) --------------
    float Slog = __logf(S0);
    float S    = __expf(Slog);
    float V    = (1.f / (1.f + __expf(-v0p[0]))) * 0.5f;
    f32x4 cv0 = {0.f, 0.f, 0.f, 0.f};
    f32x4 cv1 = {0.f, 0.f, 0.f, 0.f};
    float Slog_prev = 0.f, dS_prev = 0.f, disc1_prev = 1.f, t0_prev = 0.f;
    int   idx_prev = 0;
    bool  im_prev  = false;

    const float* zrow  = z   + (size_t)gpath * NSTEP;
    const float* zzrow = zzg + (size_t)gpath * NSTEP;

    const int path = pt * 16 + col;        // P1/B-frag path of this thread
    const int kc   = jg * 4 + quad;        // P1 k-chunk of this thread

    __syncthreads();

    auto hedge_step = [&]() {
        if (hm >= idx_prev) {
            const float slp = __shfl(Slog_prev, path);
            U8 b;
#pragma unroll
            for (int hh = 0; hh < 2; hh++) {
                const float* Wp = WH1f + (hm * 4 + quad) * 32 + hh * 4;
                const float4 wt4 = *reinterpret_cast<const float4*>(Wp);
                const float4 ws4 = *reinterpret_cast<const float4*>(Wp + 8);
                const float4 bb4 = *reinterpret_cast<const float4*>(Wp + 16);
                const float x0 = fmaxf(bb4.x + t0_prev * wt4.x + slp * ws4.x, 0.f);
                const float x1 = fmaxf(bb4.y + t0_prev * wt4.y + slp * ws4.y, 0.f);
                const float x2 = fmaxf(bb4.z + t0_prev * wt4.z + slp * ws4.z, 0.f);
                const float x3 = fmaxf(bb4.w + t0_prev * wt4.w + slp * ws4.w, 0.f);
                (&b.u.x)[2 * hh]     = pk2(x0, x1);
                (&b.u.x)[2 * hh + 1] = pk2(x2, x3);
            }
            const f32x4 z4 = {0.f, 0.f, 0.f, 0.f};
            const f32x4 D0 = __builtin_amdgcn_mfma_f32_16x16x32_bf16(Ah[0], b.v, z4, 0, 0, 0);
            const f32x4 D1 = __builtin_amdgcn_mfma_f32_16x16x32_bf16(Ah[1], b.v, z4, 0, 0, 0);
            const float dsP = __shfl(dS_prev, path);
#pragma unroll
            for (int r = 0; r < 4; r++) {
                cv0[r] += sp(D0[r] + b2h0[r]) * dsP;
                cv1[r] += sp(D1[r] + b2h1[r]) * dsP;
            }
            if (im_prev && hm == idx_prev) {
                const float Sp = __shfl(S, path);
                float p0[4], q0[4], p1[4], q1[4];
#pragma unroll
                for (int r = 0; r < 4; r++) {
                    p0[r] = disc1_prev * fmaxf(Sp - K0a[r], 0.f) - cv0[r];
                    p1[r] = disc1_prev * fmaxf(Sp - K1a[r], 0.f) - cv1[r];
                    q0[r] = p0[r] * p0[r];
                    q1[r] = p1[r] * p1[r];
                }
#pragma unroll
                for (int o = 1; o <= 8; o <<= 1) {
#pragma unroll
                    for (int r = 0; r < 4; r++) {
                        p0[r] += __shfl_xor(p0[r], o);
                        q0[r] += __shfl_xor(q0[r], o);
                        p1[r] += __shfl_xor(p1[r], o);
                        q1[r] += __shfl_xor(q1[r], o);
                    }
                }
                if (col == 0) {
#pragma unroll
                    for (int r = 0; r < 4; r++) {
                        const int s0 = quad * 4 + r, s1 = 16 + quad * 4 + r;
                        PSs[pt][s0] = p0[r];  PSq[pt][s0] = q0[r];
                        if (s1 < 21) { PSs[pt][s1] = p1[r];  PSq[pt][s1] = q1[r]; }
                    }
                }
            }
        }
    };

    auto ps_reduce = [&]() {
        if (w == 0 && im_prev) {
            const int s = lane & 31;
            if (s < 21) {
                const float* src = (lane >= 32) ? &PSq[0][0] : &PSs[0][0];
                const float acc = src[s] + src[32 + s] + src[64 + s] + src[96 + s];
                float* dst = (lane >= 32) ? psq : psum;
                dst[(idx_prev * 21 + s) * NGROUP + blockIdx.x] = acc;
            }
        }
    };

    for (int i = 0; i < NSTEP; i++) {
        const float zi  = zrow[i];
        const float zzi = zzrow[i];

        const float t0    = (float)i       * (1.f / 365.f);
        const float t1    = (float)(i + 1) * (1.f / 365.f);
        const float h     = t1 - t0;
        const float sqh   = sqrtf(h);
        const float disc0 = __expf(-rate * t0);
        const float disc1 = __expf(-rate * t1);
        const int   day   = i + 1;
        const int   idx   = (day > matr[0]) + (day > matr[1]) + (day > matr[2]);
        const bool  im    = (day == matr[idx]);

        // ===== Region 1: P1 h1 chunk | lagged hedge | vd/vv (waves 14/15) ===
        {
            const float slp = __shfl(Slog, path);
            const float vp  = __shfl(V, path);
            const float* Wp = W1f + kc * 32;
            uint4 o;
#pragma unroll
            for (int hh = 0; hh < 2; hh++) {
                const float4 a4 = *reinterpret_cast<const float4*>(Wp + hh * 4);
                const float4 b4 = *reinterpret_cast<const float4*>(Wp + 8 + hh * 4);
                const float4 c4 = *reinterpret_cast<const float4*>(Wp + 16 + hh * 4);
                const float4 d4 = *reinterpret_cast<const float4*>(Wp + 24 + hh * 4);
                const float x0 = fmaxf(d4.x + t0 * a4.x + slp * b4.x + vp * c4.x, 0.f);
                const float x1 = fmaxf(d4.y + t0 * a4.y + slp * b4.y + vp * c4.y, 0.f);
                const float x2 = fmaxf(d4.z + t0 * a4.z + slp * b4.z + vp * c4.z, 0.f);
                const float x3 = fmaxf(d4.w + t0 * a4.w + slp * b4.w + vp * c4.w, 0.f);
                (&o.x)[2 * hh]     = pk2(x0, x1);
                (&o.x)[2 * hh + 1] = pk2(x2, x3);
            }
            *reinterpret_cast<uint4*>(H1c + (kc * 64 + path) * 8) = o;
        }
        if (i > 0) hedge_step();
        if (w == 14) {
            float a2 = 0.f;
#pragma unroll
            for (int q5 = 0; q5 < 5; q5++) {
                const float4 w1 = *reinterpret_cast<const float4*>(VW + 4 * q5);
                const float4 b1 = *reinterpret_cast<const float4*>(VW + 20 + 4 * q5);
                const float4 w2 = *reinterpret_cast<const float4*>(VW + 40 + 4 * q5);
                a2 += fmaxf(V * w1.x + b1.x, 0.f) * w2.x;
                a2 += fmaxf(V * w1.y + b1.y, 0.f) * w2.y;
                a2 += fmaxf(V * w1.z + b1.z, 0.f) * w2.z;
                a2 += fmaxf(V * w1.w + b1.w, 0.f) * w2.w;
            }
            VDl[i & 1][lane] = a2;
        }
        if (w == 15) {
            float a2 = 0.f;
#pragma unroll
            for (int q5 = 0; q5 < 5; q5++) {
                const float4 w1 = *reinterpret_cast<const float4*>(VW + 64 + 4 * q5);
                const float4 b1 = *reinterpret_cast<const float4*>(VW + 84 + 4 * q5);
                const float4 w2 = *reinterpret_cast<const float4*>(VW + 104 + 4 * q5);
                a2 += fmaxf(V * w1.x + b1.x, 0.f) * w2.x;
                a2 += fmaxf(V * w1.y + b1.y, 0.f) * w2.y;
                a2 += fmaxf(V * w1.z + b1.z, 0.f) * w2.z;
                a2 += fmaxf(V * w1.w + b1.w, 0.f) * w2.w;
            }
            VVl[i & 1][lane] = a2;
        }
        __syncthreads();

        // ===== Region 2: main MFMA (A=W2T inv, B=h1) + per-lane epilogue ====
        {
            f32x4 d0 = {0.f, 0.f, 0.f, 0.f};
            f32x4 d1 = {0.f, 0.f, 0.f, 0.f};
#pragma unroll
            for (int c = 0; c < 4; c++) {
                const bf16x8 b = *reinterpret_cast<const bf16x8*>(
                    H1c + ((quad + 4 * c) * 64 + path) * 8);
                d0 = __builtin_amdgcn_mfma_f32_16x16x32_bf16(Af[c][0], b, d0, 0, 0, 0);
                d1 = __builtin_amdgcn_mfma_f32_16x16x32_bf16(Af[c][1], b, d1, 0, 0, 0);
            }
            const int j0 = (2 * jg) * 16 + quad * 4;
            const float4 b2a = *reinterpret_cast<const float4*>(B2T + j0);
            const float4 w3a = *reinterpret_cast<const float4*>(W3T + j0);
            const float4 b2b = *reinterpret_cast<const float4*>(B2T + j0 + 16);
            const float4 w3b = *reinterpret_cast<const float4*>(W3T + j0 + 16);
            float acc = fmaxf(d0[0] + b2a.x, 0.f) * w3a.x
                      + fmaxf(d0[1] + b2a.y, 0.f) * w3a.y
                      + fmaxf(d0[2] + b2a.z, 0.f) * w3a.z
                      + fmaxf(d0[3] + b2a.w, 0.f) * w3a.w
                      + fmaxf(d1[0] + b2b.x, 0.f) * w3b.x
                      + fmaxf(d1[1] + b2b.y, 0.f) * w3b.y
                      + fmaxf(d1[2] + b2b.z, 0.f) * w3b.z
                      + fmaxf(d1[3] + b2b.w, 0.f) * w3b.w;
            acc += __shfl_xor(acc, 16);
            acc += __shfl_xor(acc, 32);
            if (quad == 0)
                RED[path * 4 + jg] = acc;
        }
        ps_reduce();
        __syncthreads();

        // ===== Region 3: SDE tail (redundant per wave, state in regs) =======
        {
            const float4 rr = *reinterpret_cast<const float4*>(RED + lane * 4);
            const float pout = (rr.x + rr.y) + (rr.z + rr.w);
            const float pd = sp(pout + b3);
            const float vdv = VDl[i & 1][lane] + VW[124];
            const float vvv = sp(VVl[i & 1][lane] + VW[125]);
            const float dW = sqh * zi;
            const float dB = rho_t * dW + srho * sqh * zzi;
            const float Vn = V + vdv * h + vvv * dB;
            const float drift   = rate - 0.5f * pd * pd;
            const float diff    = pd * dW;
            const float drift_c = 1.f + fabsf(drift) * sqh;
            const float diff_c  = 1.f + fabsf(pd) * sqh;
            const float Sln = Slog + __fdividef(drift * h, drift_c) + __fdividef(diff, diff_c);
            const float Sn  = __expf(Sln);
            const float dS  = disc1 * Sn - disc0 * S;
            Slog_prev = Slog; dS_prev = dS; disc1_prev = disc1; t0_prev = t0;
            idx_prev = idx; im_prev = im;
            Slog = Sln; S = Sn; V = Vn;
        }
    }

    hedge_step();
    __syncthreads();
    ps_reduce();
}

__global__ void lsv_finalize(const float* __restrict__ psum,
                             const float* __restrict__ psq,
                             float* __restrict__ out)
{
    const int t = blockIdx.x * blockDim.x + threadIdx.x;
    if (t >= NPAIR) return;
    float s = 0.f, q = 0.f;
    for (int b = 0; b < NGROUP; b++) {
        s += psum[t * NGROUP + b];
        q += psq [t * NGROUP + b];
    }
    const float mean = s * (1.0f / (float)MC);
    const float var  = (q - (float)MC * mean * mean) * (1.0f / (float)(MC - 1));
    out[t]         = mean;
    out[NPAIR + t] = var;
}

extern "C" void kernel_launch(void* const* d_in, const int* in_sizes, int n_in,
                              void* d_out, int out_size, void* d_ws, size_t ws_size,
                              hipStream_t stream)
{
    const float* S0    = (const float*)d_in[0];
    const float* rate  = (const float*)d_in[1];
    const float* z     = (const float*)d_in[2];
    const float* zz    = (const float*)d_in[3];
    const float* strikes = (const float*)d_in[5];
    const float* v0    = (const float*)d_in[6];
    const float* rho   = (const float*)d_in[7];
    const float* svW1  = (const float*)d_in[8];
    const float* svb1  = (const float*)d_in[9];
    const float* svW2  = (const float*)d_in[10];
    const float* svb2  = (const float*)d_in[11];
    const float* svW3  = (const float*)d_in[12];
    const float* svb3  = (const float*)d_in[13];
    const float* vhW1  = (const float*)d_in[14];
    const float* vhb1  = (const float*)d_in[15];
    const float* vhW2  = (const float*)d_in[16];
    const float* vhb2  = (const float*)d_in[17];
    const float* vdW1  = (const float*)d_in[18];
    const float* vdb1  = (const float*)d_in[19];
    const float* vdW2  = (const float*)d_in[20];
    const float* vdb2  = (const float*)d_in[21];
    const float* vvW1  = (const float*)d_in[22];
    const float* vvb1  = (const float*)d_in[23];
    const float* vvW2  = (const float*)d_in[24];
    const float* vvb2  = (const float*)d_in[25];
    const int*   mats  = (const int*)d_in[26];

    float* psum = (float*)d_ws;
    float* psq  = psum + NPAIR * NGROUP;

    hipLaunchKernelGGL(lsv_sim, dim3(NGROUP), dim3(BLOCK), 0, stream,
                       S0, rate, z, zz, strikes, v0, rho,
                       svW1, svb1, svW2, svb2, svW3, svb3,
                       vhW1, vhb1, vhW2, vhb2,
                       vdW1, vdb1, vdW2, vdb2,
                       vvW1, vvb1, vvW2, vvb2,
                       mats, psum, psq);

    hipLaunchKernelGGL(lsv_finalize, dim3(1), dim3(128), 0, stream,
                       psum, psq, (float*)d_out);
}